// Round 3
// baseline (589.457 us; speedup 1.0000x reference)
//
#include <hip/hip_runtime.h>

// CondConv2d: N=8, C_IN=C_OUT=64, H=W=128, K=4 experts, 3x3, pad 1, stride 1.
// f32 in/out; bf16 MFMA compute with f32 accumulate.
// Identity: out = conv2d(x, conv_w + sum_k att[n,k]*weight[k]) + conv_b
//
// *** ROUND-3 CALIBRATION PROBE ***
// kC's inner (ds_read+MFMA) loop runs REP=8 times, epilogue scales by 1/8
// (exact: power-of-two). Purpose: make kC visible in the top-5 rocprof rows
// (currently saturated by 42us harness fills) and calibrate:
//   T_inner   = (dur_us - 129.7)/7
//   kC_base   = kC_visible - 7*T_inner
//   iteration period from consecutive kC Start_Timestamps -> are fills timed?
// Everything else identical to the round-2 kernel (which passed, 129.7us).

typedef unsigned short ushort_t;
typedef __attribute__((ext_vector_type(8))) short bf16x8;
typedef __attribute__((ext_vector_type(4))) float f32x4;

__device__ __forceinline__ ushort_t f2bf(float f) {
    unsigned u = __float_as_uint(f);
    unsigned r = (u + 0x7fffu + ((u >> 16) & 1u)) >> 16;   // RNE
    return (ushort_t)r;
}

__device__ __forceinline__ void gl_lds16(const ushort_t* g, ushort_t* l) {
    __builtin_amdgcn_global_load_lds(
        (const __attribute__((address_space(1))) unsigned*)g,
        (__attribute__((address_space(3))) unsigned*)l, 16, 0, 0);
}

// ---------------------------------------------------------------------------
// kTR: block per (n,h). Thread (ci8=tid>>5, wg=tid&31) loads 8ci x 4w scalar
// dwords (coalesced), packs bf16x8, writes xt_pad contiguous 16B chunks at
// (h'=h+1, w'=w+1). Zero halo. Per-row routing stats -> part.
__global__ __launch_bounds__(256) void kTR(const float* __restrict__ x,
                                           ushort_t* __restrict__ xt,
                                           float* __restrict__ part) {
    int row = blockIdx.x;                 // n*128 + h
    int h = row & 127, n = row >> 7;
    int tid = threadIdx.x;
    int wg = tid & 31;                    // w lane (w = wg + 32c)
    int ci8 = tid >> 5;                   // 0..7

    __shared__ float catloc[15];
    if (tid < 15) catloc[tid] = 0.f;
    __syncthreads();

    const float* xp = x + (size_t)(n * 64 + ci8 * 8) * 16384 + h * 128 + wg;
    float v[8][4];
#pragma unroll
    for (int j = 0; j < 8; ++j)
#pragma unroll
        for (int c = 0; c < 4; ++c)
            v[j][c] = xp[j * 16384 + c * 32];

    // xt_pad writes: [n][h+1][ci8][w+1][8ci], row pitch 130 chunks of 16B
    ushort_t* op = xt + (((size_t)(n * 130 + h + 1) * 8 + ci8) * 130 + 1) * 8;
#pragma unroll
    for (int c = 0; c < 4; ++c) {
        ushort_t u[8];
#pragma unroll
        for (int j = 0; j < 8; ++j) u[j] = f2bf(v[j][c]);
        uint4 pk;
        pk.x = (unsigned)u[0] | ((unsigned)u[1] << 16);
        pk.y = (unsigned)u[2] | ((unsigned)u[3] << 16);
        pk.z = (unsigned)u[4] | ((unsigned)u[5] << 16);
        pk.w = (unsigned)u[6] | ((unsigned)u[7] << 16);
        *(uint4*)(op + (size_t)(wg + c * 32) * 8) = pk;
    }

    // zero halo: w'=0 and w'=129 of this h' row (all 8 ci8 rows)
    if (tid < 16) {
        int cib = tid & 7, side = tid >> 3;
        *(uint4*)(xt + (((size_t)(n * 130 + h + 1) * 8 + cib) * 130 + side * 129) * 8)
            = make_uint4(0u, 0u, 0u, 0u);
    }
    // zero halo: full h'=0 / h'=129 rows (1040 chunks each)
    if (h == 0 || h == 127) {
        int hp = (h == 0) ? 0 : 129;
        size_t base = (size_t)(n * 130 + hp) * 8 * 130;
        for (int ii = tid; ii < 1040; ii += 256)
            *(uint4*)(xt + (base + ii) * 8) = make_uint4(0u, 0u, 0u, 0u);
    }

    // routing sums: per-ci row sum + boundary cols
#pragma unroll
    for (int j = 0; j < 8; ++j) {
        float rs = v[j][0] + v[j][1] + v[j][2] + v[j][3];
#pragma unroll
        for (int m = 1; m <= 16; m <<= 1) rs += __shfl_xor(rs, m);
        int ci = ci8 * 8 + j;
        int cd = (ci == 0) ? 0 : (ci == 1) ? 1 : (ci == 62) ? 3 : (ci == 63) ? 4 : 2;
        if (wg == 0) {
            atomicAdd(&catloc[cd * 3 + 0], rs);
            atomicAdd(&catloc[cd * 3 + 1], v[j][0]);            // w == 0
        }
        if (wg == 31) atomicAdd(&catloc[cd * 3 + 2], v[j][3]);  // w == 127
    }
    __syncthreads();
    if (tid < 15) part[row * 16 + tid] = catloc[tid];
}

// ---------------------------------------------------------------------------
// kW: block per (n,s,q). Reduce part rows -> cat; 45 box-sums in parallel;
// logits+softmax; Weff[n][s][co][ci] for 4 co per block.
__global__ __launch_bounds__(256) void kW(const float* __restrict__ part,
                                          const float* __restrict__ nw0, const float* __restrict__ nb0,
                                          const float* __restrict__ nw1, const float* __restrict__ nb1,
                                          const float* __restrict__ nw2, const float* __restrict__ nb2,
                                          const float* __restrict__ weight,
                                          const float* __restrict__ convw,
                                          ushort_t* __restrict__ weff) {
    int bid = blockIdx.x;                 // (n*9 + s)*4 + q
    int q = bid & 3;
    int ns = bid >> 2;
    int s = ns % 9;
    int n = ns / 9;
    int tid = threadIdx.x;

    __shared__ float cat_s[45];           // [cd][ch][st]
    __shared__ float box_s[45];
    __shared__ float tot_s;
    __shared__ float att_s[4];

    if (tid < 45) cat_s[tid] = 0.f;
    __syncthreads();
    if (tid < 128) {
        int h = tid;
        int ch = (h == 0) ? 0 : (h == 127) ? 2 : 1;
        const float* pp = part + (size_t)(n * 128 + h) * 16;
#pragma unroll
        for (int p = 0; p < 15; ++p) {
            int cd = p / 3, st = p % 3;
            atomicAdd(&cat_s[(cd * 3 + ch) * 3 + st], pp[p]);
        }
    }
    __syncthreads();

    if (tid < 46) {
        float c[5][3][3];
#pragma unroll
        for (int i = 0; i < 5; ++i)
#pragma unroll
            for (int j = 0; j < 3; ++j)
#pragma unroll
                for (int t = 0; t < 3; ++t)
                    c[i][j][t] = cat_s[(i * 3 + j) * 3 + t];

        if (tid < 45) {
            int dz = tid / 9 - 2;
            int dy = (tid / 3) % 3 - 1;
            int dx = tid % 3 - 1;
            float acc = 0.f;
#pragma unroll
            for (int cd = 0; cd < 5; ++cd) {
                int dv = (cd == 0) ? 0 : (cd == 1) ? 1 : (cd == 3) ? 62 : (cd == 4) ? 63 : -1;
                bool incd = (dv < 0) || (dv >= dz && dv < 64 + dz);
#pragma unroll
                for (int ch = 0; ch < 3; ++ch) {
                    int hv = (ch == 0) ? 0 : (ch == 2) ? 127 : -1;
                    bool inch = (hv < 0) || (hv >= dy && hv < 128 + dy);
                    if (incd && inch) {
                        float vv = c[cd][ch][0];
                        if (dx == -1) vv -= c[cd][ch][2];
                        else if (dx == 1) vv -= c[cd][ch][1];
                        acc += vv;
                    }
                }
            }
            box_s[tid] = acc;
        } else {
            float tot = 0.f;
#pragma unroll
            for (int i = 0; i < 5; ++i)
#pragma unroll
                for (int j = 0; j < 3; ++j) tot += c[i][j][0];
            tot_s = tot;
        }
    }
    __syncthreads();

    if (tid < 4) {
        int k = tid;
        const float invV = 1.0f / (64.f * 128.f * 128.f);
        float lg = nb0[k] + nb1[k] + nb2[k] + nw0[k] * tot_s * invV;
#pragma unroll
        for (int dz = 0; dz < 3; ++dz)
#pragma unroll
            for (int dy = 0; dy < 3; ++dy)
#pragma unroll
                for (int dx = 0; dx < 3; ++dx)
                    lg += nw1[k * 27 + dz * 9 + dy * 3 + dx] *
                          box_s[(dz + 1) * 9 + dy * 3 + dx] * invV;
#pragma unroll
        for (int b = 0; b < 45; ++b)
            lg += nw2[k * 45 + b] * box_s[b] * invV;

        float m = fmaxf(lg, __shfl_xor(lg, 1));
        m = fmaxf(m, __shfl_xor(m, 2));
        float e = __expf(lg - m);
        float ssum = e + __shfl_xor(e, 1);
        ssum += __shfl_xor(ssum, 2);
        att_s[k] = e / ssum;
    }
    __syncthreads();

    float a0 = att_s[0], a1 = att_s[1], a2 = att_s[2], a3 = att_s[3];
    int ci = tid & 63;
    int cog = tid >> 6;
    ushort_t* wp = weff + ((size_t)(n * 9 + s) * 64) * 64;
#pragma unroll
    for (int p = 0; p < 4; ++p) {
        int co = cog * 16 + q * 4 + p;
        size_t base = (size_t)(co * 64 + ci) * 9 + s;
        float v = convw[base]
                + a0 * weight[base]
                + a1 * weight[base +     64 * 64 * 9]
                + a2 * weight[base + 2 * 64 * 64 * 9]
                + a3 * weight[base + 3 * 64 * 64 * 9];
        wp[(size_t)co * 64 + ci] = f2bf(v);
    }
}

// ---------------------------------------------------------------------------
// kC: main conv with REP=8 inner-loop repetition (calibration probe).
// Block decode XCD-swizzled: n = bid&7. 64co x (4h x 64w) tile.
// LDS: 6 rows x [ci8(8)][66 w][8ci] = 50688 B, bulk via global_load_lds.
__global__ __launch_bounds__(256, 2) void kC(const ushort_t* __restrict__ xt,
                                             const ushort_t* __restrict__ weff,
                                             const float* __restrict__ convb,
                                             float* __restrict__ out) {
    int b = blockIdx.x;
    int n = b & 7;                        // == XCD id under round-robin dispatch
    int r2 = b >> 3;
    int wt = r2 & 1;
    int hq = r2 >> 1;                     // 0..31
    int h0 = hq * 4;
    int w0 = wt * 64;

    __shared__ __align__(16) ushort_t lds[6 * 8 * 66 * 8];   // 50688 B

    int tid = threadIdx.x;
    int lane = tid & 63;
    int wave = tid >> 6;                  // co tile
    int kq = lane >> 4;                   // quad 0..3
    int l15 = lane & 15;

    // async stage (full waves): 3072 chunks of 16B; chunk = (r*8+ci8)*66 + c
    size_t sbase = ((size_t)(n * 130 + h0) * 8) * 130 + w0;
#pragma unroll
    for (int m = 0; m < 12; ++m) {
        int chunk = m * 256 + tid;
        int c = chunk % 66;
        int rc8 = chunk / 66;             // r*8 + ci8
        size_t so = sbase + (size_t)(rc8 >> 3) * 1040 + (size_t)(rc8 & 7) * 130 + c;
        gl_lds16(xt + so * 8, &lds[(size_t)chunk * 8]);
    }
    // tail: chunks 3072..3167, reg-staged (avoids partial-wave DMA semantics)
    uint4 tail_v;
    int tail_chunk = 3072 + tid;
    if (tid < 96) {
        int c = tail_chunk % 66;
        int rc8 = tail_chunk / 66;
        size_t so = sbase + (size_t)(rc8 >> 3) * 1040 + (size_t)(rc8 & 7) * 130 + c;
        tail_v = *(const uint4*)(xt + so * 8);
    }

    // A fragments (Weff): 18 x 16B = 72 VGPRs — issued while DMA in flight
    int co_a = wave * 16 + l15;
    bf16x8 afrag[9][2];
#pragma unroll
    for (int s = 0; s < 9; ++s)
#pragma unroll
        for (int kc = 0; kc < 2; ++kc)
            afrag[s][kc] = *(const bf16x8*)(weff +
                ((size_t)((n * 9 + s) * 64 + co_a)) * 64 + kc * 32 + kq * 8);

    if (tid < 96) *(uint4*)&lds[(size_t)tail_chunk * 8] = tail_v;

    f32x4 acc[16];
#pragma unroll
    for (int t = 0; t < 16; ++t) acc[t] = (f32x4){0.f, 0.f, 0.f, 0.f};

    __syncthreads();                      // drains vmcnt (DMA + loads) + lgkm + barrier

    // PROBE: run the inner loop 8x (not unrolled), scale by 1/8 at epilogue.
#pragma unroll 1
    for (int rep = 0; rep < 8; ++rep) {
#pragma unroll
        for (int kx = 0; kx < 3; ++kx) {
#pragma unroll
            for (int kc = 0; kc < 2; ++kc) {
#pragma unroll
                for (int col = 0; col < 4; ++col) {
                    bf16x8 brow[6];
#pragma unroll
                    for (int p = 0; p < 6; ++p)
                        brow[p] = *(const bf16x8*)
                            &lds[(((p * 8 + kc * 4 + kq) * 66) + col * 16 + l15 + kx) * 8];
#pragma unroll
                    for (int ky = 0; ky < 3; ++ky)
#pragma unroll
                        for (int r = 0; r < 4; ++r)
                            acc[r * 4 + col] = __builtin_amdgcn_mfma_f32_16x16x32_bf16(
                                afrag[ky * 3 + kx][kc], brow[r + ky], acc[r * 4 + col], 0, 0, 0);
                }
            }
        }
    }

    // epilogue: D row(=co) = kq*4+reg, col(=w) = l15; scale 1/8 (exact)
#pragma unroll
    for (int r = 0; r < 4; ++r) {
        int h = h0 + r;
#pragma unroll
        for (int col = 0; col < 4; ++col) {
            int w = w0 + col * 16 + l15;
#pragma unroll
            for (int reg = 0; reg < 4; ++reg) {
                int co = wave * 16 + kq * 4 + reg;
                float v = acc[r * 4 + col][reg] * 0.125f + convb[co];
                out[(((size_t)n * 64 + co) * 128 + h) * 128 + w] = v;
            }
        }
    }
}

// ---------------------------------------------------------------------------
extern "C" void kernel_launch(void* const* d_in, const int* in_sizes, int n_in,
                              void* d_out, int out_size, void* d_ws, size_t ws_size,
                              hipStream_t stream) {
    const float* x      = (const float*)d_in[0];
    const float* weight = (const float*)d_in[1];
    const float* conv_w = (const float*)d_in[2];
    const float* conv_b = (const float*)d_in[3];
    const float* n0w    = (const float*)d_in[4];
    const float* n0b    = (const float*)d_in[5];
    const float* n1w    = (const float*)d_in[6];
    const float* n1b    = (const float*)d_in[7];
    const float* n2w    = (const float*)d_in[8];
    const float* n2b    = (const float*)d_in[9];
    float* out = (float*)d_out;

    char* ws = (char*)d_ws;
    ushort_t* xt   = (ushort_t*)(ws);                        // 17,305,600 B (padded)
    ushort_t* weff = (ushort_t*)(ws + 17305600);             // 589,824 B
    float*    part = (float*)(ws + 17305600 + 589824);       // 65,536 B

    kTR<<<1024, 256, 0, stream>>>(x, xt, part);
    kW<<<288, 256, 0, stream>>>(part, n0w, n0b, n1w, n1b, n2w, n2b,
                                weight, conv_w, weff);
    kC<<<512, 256, 0, stream>>>(xt, weff, conv_b, out);
}

// Round 4
// 128.749 us; speedup vs baseline: 4.5783x; 4.5783x over previous
//
#include <hip/hip_runtime.h>

// CondConv2d: N=8, C_IN=C_OUT=64, H=W=128, K=4 experts, 3x3, pad 1, stride 1.
// f32 in/out; bf16 MFMA compute with f32 accumulate.
// Identity: out = conv2d(x, conv_w + sum_k att[n,k]*weight[k]) + conv_b
// Routing logits = closed-form box-sums of x (mean-pooled C=1 3D convs).
// Pipeline (3 dispatches, no memset):
//   kTR: transpose x -> xt_pad (bf16 [n][130 h'][ci8][130 w'][8ci], zero halo)
//        + per-row stats -> part
//   kW : reduce part -> att -> Weff[n][s][co][ci] bf16 (576 blocks, 2 co each)
//   kC : MFMA conv, 64co x (4h x 64w) tiles; staging via global_load_lds;
//        A-fragments loaded PER-kx (24 live VGPRs, not 72) to stay under the
//        128-reg boundary — round-3 probe showed the all-live variant spills
//        (940MB scratch reads/dispatch). XCD-swizzled bid: each XCD owns one n.
// Round-3 calibration: base kC ~7us, kTR+kW ~13us; the other ~110us of the
// timed window is harness ws-poison fills (2 x 42us @ 80% HBM) + gaps.
// NOTE: hipLaunchCooperativeKernel fails under the harness graph capture
// (silent no-op, R5) — regular dispatches only.

typedef unsigned short ushort_t;
typedef __attribute__((ext_vector_type(8))) short bf16x8;
typedef __attribute__((ext_vector_type(4))) float f32x4;

__device__ __forceinline__ ushort_t f2bf(float f) {
    unsigned u = __float_as_uint(f);
    unsigned r = (u + 0x7fffu + ((u >> 16) & 1u)) >> 16;   // RNE
    return (ushort_t)r;
}

__device__ __forceinline__ void gl_lds16(const ushort_t* g, ushort_t* l) {
    __builtin_amdgcn_global_load_lds(
        (const __attribute__((address_space(1))) unsigned*)g,
        (__attribute__((address_space(3))) unsigned*)l, 16, 0, 0);
}

// ---------------------------------------------------------------------------
// kTR: block per (n,h). Thread (ci8=tid>>5, wg=tid&31) loads 8ci x 4w scalar
// dwords (coalesced), packs bf16x8, writes xt_pad contiguous 16B chunks at
// (h'=h+1, w'=w+1). Zero halo. Per-row routing stats -> part.
__global__ __launch_bounds__(256) void kTR(const float* __restrict__ x,
                                           ushort_t* __restrict__ xt,
                                           float* __restrict__ part) {
    int row = blockIdx.x;                 // n*128 + h
    int h = row & 127, n = row >> 7;
    int tid = threadIdx.x;
    int wg = tid & 31;                    // w lane (w = wg + 32c)
    int ci8 = tid >> 5;                   // 0..7

    __shared__ float catloc[15];
    if (tid < 15) catloc[tid] = 0.f;
    __syncthreads();

    const float* xp = x + (size_t)(n * 64 + ci8 * 8) * 16384 + h * 128 + wg;
    float v[8][4];
#pragma unroll
    for (int j = 0; j < 8; ++j)
#pragma unroll
        for (int c = 0; c < 4; ++c)
            v[j][c] = xp[j * 16384 + c * 32];

    // xt_pad writes: [n][h+1][ci8][w+1][8ci], row pitch 130 chunks of 16B
    ushort_t* op = xt + (((size_t)(n * 130 + h + 1) * 8 + ci8) * 130 + 1) * 8;
#pragma unroll
    for (int c = 0; c < 4; ++c) {
        ushort_t u[8];
#pragma unroll
        for (int j = 0; j < 8; ++j) u[j] = f2bf(v[j][c]);
        uint4 pk;
        pk.x = (unsigned)u[0] | ((unsigned)u[1] << 16);
        pk.y = (unsigned)u[2] | ((unsigned)u[3] << 16);
        pk.z = (unsigned)u[4] | ((unsigned)u[5] << 16);
        pk.w = (unsigned)u[6] | ((unsigned)u[7] << 16);
        *(uint4*)(op + (size_t)(wg + c * 32) * 8) = pk;
    }

    // zero halo: w'=0 and w'=129 of this h' row (all 8 ci8 rows)
    if (tid < 16) {
        int cib = tid & 7, side = tid >> 3;
        *(uint4*)(xt + (((size_t)(n * 130 + h + 1) * 8 + cib) * 130 + side * 129) * 8)
            = make_uint4(0u, 0u, 0u, 0u);
    }
    // zero halo: full h'=0 / h'=129 rows (1040 chunks each)
    if (h == 0 || h == 127) {
        int hp = (h == 0) ? 0 : 129;
        size_t base = (size_t)(n * 130 + hp) * 8 * 130;
        for (int ii = tid; ii < 1040; ii += 256)
            *(uint4*)(xt + (base + ii) * 8) = make_uint4(0u, 0u, 0u, 0u);
    }

    // routing sums: per-ci row sum + boundary cols
#pragma unroll
    for (int j = 0; j < 8; ++j) {
        float rs = v[j][0] + v[j][1] + v[j][2] + v[j][3];
#pragma unroll
        for (int m = 1; m <= 16; m <<= 1) rs += __shfl_xor(rs, m);
        int ci = ci8 * 8 + j;
        int cd = (ci == 0) ? 0 : (ci == 1) ? 1 : (ci == 62) ? 3 : (ci == 63) ? 4 : 2;
        if (wg == 0) {
            atomicAdd(&catloc[cd * 3 + 0], rs);
            atomicAdd(&catloc[cd * 3 + 1], v[j][0]);            // w == 0
        }
        if (wg == 31) atomicAdd(&catloc[cd * 3 + 2], v[j][3]);  // w == 127
    }
    __syncthreads();
    if (tid < 15) part[row * 16 + tid] = catloc[tid];
}

// ---------------------------------------------------------------------------
// kW: block per (n,s,q), q in 0..7. Reduce part rows -> cat (staggered LDS
// atomics to break the 42-way same-cell bursts); 45 box-sums in parallel;
// logits+softmax (redundant across q, trivial); Weff[n][s][co][ci] for 2 co
// per thread. 576 blocks => ~2.3 waves/SIMD so the stride-9 gathers have
// latency hiding.
__global__ __launch_bounds__(256) void kW(const float* __restrict__ part,
                                          const float* __restrict__ nw0, const float* __restrict__ nb0,
                                          const float* __restrict__ nw1, const float* __restrict__ nb1,
                                          const float* __restrict__ nw2, const float* __restrict__ nb2,
                                          const float* __restrict__ weight,
                                          const float* __restrict__ convw,
                                          ushort_t* __restrict__ weff) {
    int bid = blockIdx.x;                 // (n*9 + s)*8 + q
    int q = bid & 7;
    int ns = bid >> 3;
    int s = ns % 9;
    int n = ns / 9;
    int tid = threadIdx.x;

    __shared__ float cat_s[45];           // [cd][ch][st]
    __shared__ float box_s[45];
    __shared__ float tot_s;
    __shared__ float att_s[4];

    if (tid < 45) cat_s[tid] = 0.f;
    __syncthreads();
    if (tid < 128) {
        int h = tid;
        int ch = (h == 0) ? 0 : (h == 127) ? 2 : 1;
        const float* pp = part + (size_t)(n * 128 + h) * 16;
#pragma unroll
        for (int q0 = 0; q0 < 15; ++q0) {
            int p = (q0 + h) % 15;        // stagger: spread collisions in time
            int cd = p / 3, st = p % 3;
            atomicAdd(&cat_s[(cd * 3 + ch) * 3 + st], pp[p]);
        }
    }
    __syncthreads();

    if (tid < 46) {
        float c[5][3][3];
#pragma unroll
        for (int i = 0; i < 5; ++i)
#pragma unroll
            for (int j = 0; j < 3; ++j)
#pragma unroll
                for (int t = 0; t < 3; ++t)
                    c[i][j][t] = cat_s[(i * 3 + j) * 3 + t];

        if (tid < 45) {
            int dz = tid / 9 - 2;
            int dy = (tid / 3) % 3 - 1;
            int dx = tid % 3 - 1;
            float acc = 0.f;
#pragma unroll
            for (int cd = 0; cd < 5; ++cd) {
                int dv = (cd == 0) ? 0 : (cd == 1) ? 1 : (cd == 3) ? 62 : (cd == 4) ? 63 : -1;
                bool incd = (dv < 0) || (dv >= dz && dv < 64 + dz);
#pragma unroll
                for (int ch = 0; ch < 3; ++ch) {
                    int hv = (ch == 0) ? 0 : (ch == 2) ? 127 : -1;
                    bool inch = (hv < 0) || (hv >= dy && hv < 128 + dy);
                    if (incd && inch) {
                        float vv = c[cd][ch][0];
                        if (dx == -1) vv -= c[cd][ch][2];
                        else if (dx == 1) vv -= c[cd][ch][1];
                        acc += vv;
                    }
                }
            }
            box_s[tid] = acc;
        } else {
            float tot = 0.f;
#pragma unroll
            for (int i = 0; i < 5; ++i)
#pragma unroll
                for (int j = 0; j < 3; ++j) tot += c[i][j][0];
            tot_s = tot;
        }
    }
    __syncthreads();

    if (tid < 4) {
        int k = tid;
        const float invV = 1.0f / (64.f * 128.f * 128.f);
        float lg = nb0[k] + nb1[k] + nb2[k] + nw0[k] * tot_s * invV;
#pragma unroll
        for (int dz = 0; dz < 3; ++dz)
#pragma unroll
            for (int dy = 0; dy < 3; ++dy)
#pragma unroll
                for (int dx = 0; dx < 3; ++dx)
                    lg += nw1[k * 27 + dz * 9 + dy * 3 + dx] *
                          box_s[(dz + 1) * 9 + dy * 3 + dx] * invV;
#pragma unroll
        for (int b = 0; b < 45; ++b)
            lg += nw2[k * 45 + b] * box_s[b] * invV;

        float m = fmaxf(lg, __shfl_xor(lg, 1));
        m = fmaxf(m, __shfl_xor(m, 2));
        float e = __expf(lg - m);
        float ssum = e + __shfl_xor(e, 1);
        ssum += __shfl_xor(ssum, 2);
        att_s[k] = e / ssum;
    }
    __syncthreads();

    float a0 = att_s[0], a1 = att_s[1], a2 = att_s[2], a3 = att_s[3];
    int ci = tid & 63;
    int cog = tid >> 6;
    ushort_t* wp = weff + ((size_t)(n * 9 + s) * 64) * 64;
#pragma unroll
    for (int p = 0; p < 2; ++p) {
        int co = cog * 16 + q * 2 + p;
        size_t base = (size_t)(co * 64 + ci) * 9 + s;
        float v = convw[base]
                + a0 * weight[base]
                + a1 * weight[base +     64 * 64 * 9]
                + a2 * weight[base + 2 * 64 * 64 * 9]
                + a3 * weight[base + 3 * 64 * 64 * 9];
        wp[(size_t)co * 64 + ci] = f2bf(v);
    }
}

// ---------------------------------------------------------------------------
// kC: main conv. Block decode XCD-swizzled: n = bid&7 so XCD k owns sample k
// (xt[n] 2.1MB + weff[n] 74KB stay in that XCD's 4MB L2). 64co x (4h x 64w)
// tile. LDS: 6 rows x [ci8(8)][66 w][8ci] = 50688 B. Bulk (3072 chunks) via
// async global_load_lds with FULL waves; 96-chunk tail reg-staged.
// A-fragments loaded per-kx (6 live = 24 VGPRs): total pressure ~130 vs the
// spilling 175 of the all-live variant (round-3 probe evidence). LDS caps
// occupancy at 3 blocks/CU regardless, so fewer regs buys nothing — no-spill
// is the only goal. Inner loop: per (kx,kc,col) 6 ds_read_b128 -> 12 MFMAs.
__global__ __launch_bounds__(256, 2) void kC(const ushort_t* __restrict__ xt,
                                             const ushort_t* __restrict__ weff,
                                             const float* __restrict__ convb,
                                             float* __restrict__ out) {
    int b = blockIdx.x;
    int n = b & 7;                        // == XCD id under round-robin dispatch
    int r2 = b >> 3;
    int wt = r2 & 1;
    int hq = r2 >> 1;                     // 0..31
    int h0 = hq * 4;
    int w0 = wt * 64;

    __shared__ __align__(16) ushort_t lds[6 * 8 * 66 * 8];   // 50688 B

    int tid = threadIdx.x;
    int lane = tid & 63;
    int wave = tid >> 6;                  // co tile
    int kq = lane >> 4;                   // quad 0..3
    int l15 = lane & 15;

    // async stage (full waves): 3072 chunks of 16B; chunk = (r*8+ci8)*66 + c
    // src chunk offset = ((n*130 + h0 + r)*8 + ci8)*130 + w0 + c
    size_t sbase = ((size_t)(n * 130 + h0) * 8) * 130 + w0;
#pragma unroll
    for (int m = 0; m < 12; ++m) {
        int chunk = m * 256 + tid;
        int c = chunk % 66;
        int rc8 = chunk / 66;             // r*8 + ci8
        size_t so = sbase + (size_t)(rc8 >> 3) * 1040 + (size_t)(rc8 & 7) * 130 + c;
        gl_lds16(xt + so * 8, &lds[(size_t)chunk * 8]);
    }
    // tail: chunks 3072..3167, reg-staged (avoids partial-wave DMA semantics)
    uint4 tail_v;
    int tail_chunk = 3072 + tid;
    if (tid < 96) {
        int c = tail_chunk % 66;
        int rc8 = tail_chunk / 66;
        size_t so = sbase + (size_t)(rc8 >> 3) * 1040 + (size_t)(rc8 & 7) * 130 + c;
        tail_v = *(const uint4*)(xt + so * 8);
    }

    int co_a = wave * 16 + l15;

    if (tid < 96) *(uint4*)&lds[(size_t)tail_chunk * 8] = tail_v;

    f32x4 acc[16];
#pragma unroll
    for (int t = 0; t < 16; ++t) acc[t] = (f32x4){0.f, 0.f, 0.f, 0.f};

    __syncthreads();                      // drains vmcnt (DMA + loads) + lgkm + barrier

    // inner: register-cached B rows; A-fragments fetched per-kx (L2-warm weff)
#pragma unroll
    for (int kx = 0; kx < 3; ++kx) {
        bf16x8 afx[3][2];                 // [ky][kc] — only 6 frags live
#pragma unroll
        for (int ky = 0; ky < 3; ++ky)
#pragma unroll
            for (int kc = 0; kc < 2; ++kc)
                afx[ky][kc] = *(const bf16x8*)(weff +
                    ((size_t)((n * 9 + ky * 3 + kx) * 64 + co_a)) * 64 + kc * 32 + kq * 8);
#pragma unroll
        for (int kc = 0; kc < 2; ++kc) {
#pragma unroll
            for (int col = 0; col < 4; ++col) {
                bf16x8 brow[6];
#pragma unroll
                for (int p = 0; p < 6; ++p)
                    brow[p] = *(const bf16x8*)
                        &lds[(((p * 8 + kc * 4 + kq) * 66) + col * 16 + l15 + kx) * 8];
#pragma unroll
                for (int ky = 0; ky < 3; ++ky)
#pragma unroll
                    for (int r = 0; r < 4; ++r)
                        acc[r * 4 + col] = __builtin_amdgcn_mfma_f32_16x16x32_bf16(
                            afx[ky][kc], brow[r + ky], acc[r * 4 + col], 0, 0, 0);
            }
        }
    }

    // epilogue: D row(=co) = kq*4+reg, col(=w) = l15
#pragma unroll
    for (int r = 0; r < 4; ++r) {
        int h = h0 + r;
#pragma unroll
        for (int col = 0; col < 4; ++col) {
            int w = w0 + col * 16 + l15;
#pragma unroll
            for (int reg = 0; reg < 4; ++reg) {
                int co = wave * 16 + kq * 4 + reg;
                float v = acc[r * 4 + col][reg] + convb[co];
                out[(((size_t)n * 64 + co) * 128 + h) * 128 + w] = v;
            }
        }
    }
}

// ---------------------------------------------------------------------------
extern "C" void kernel_launch(void* const* d_in, const int* in_sizes, int n_in,
                              void* d_out, int out_size, void* d_ws, size_t ws_size,
                              hipStream_t stream) {
    const float* x      = (const float*)d_in[0];
    const float* weight = (const float*)d_in[1];
    const float* conv_w = (const float*)d_in[2];
    const float* conv_b = (const float*)d_in[3];
    const float* n0w    = (const float*)d_in[4];
    const float* n0b    = (const float*)d_in[5];
    const float* n1w    = (const float*)d_in[6];
    const float* n1b    = (const float*)d_in[7];
    const float* n2w    = (const float*)d_in[8];
    const float* n2b    = (const float*)d_in[9];
    float* out = (float*)d_out;

    char* ws = (char*)d_ws;
    ushort_t* xt   = (ushort_t*)(ws);                        // 17,305,600 B (padded)
    ushort_t* weff = (ushort_t*)(ws + 17305600);             // 589,824 B
    float*    part = (float*)(ws + 17305600 + 589824);       // 65,536 B

    kTR<<<1024, 256, 0, stream>>>(x, xt, part);
    kW<<<576, 256, 0, stream>>>(part, n0w, n0b, n1w, n1b, n2w, n2b,
                                weight, conv_w, weff);
    kC<<<512, 256, 0, stream>>>(xt, weff, conv_b, out);
}